// Round 8
// baseline (327.494 us; speedup 1.0000x reference)
//
#include <hip/hip_runtime.h>
#include <math.h>

typedef __attribute__((ext_vector_type(8))) short short8;
typedef __attribute__((ext_vector_type(4))) float f32x4;
#define MFMA __builtin_amdgcn_mfma_f32_16x16x32_bf16

#define BN_EPS 1e-5f

// ---------------- workspace layout (float offsets) ----------------
// w1c2: 2048 u16   [n2][ol16][kc4][p2][e8]
// w2c2: 36864 u16  [tap9][n4][ol16][kc4][p2][e8]
// w3c2: 147456 u16 [tap9][s2][nf8][ol16][kc4][p2][e8]
// pxp : packed x (hi<<16|lo) u32[4096*3072 + 64 guard]
static const size_t W1C2_OFF = 0;
static const size_t W2C2_OFF = 1024;
static const size_t W3C2_OFF = 19456;
static const size_t B1_OFF   = 93184;
static const size_t B2_OFF   = 93216;
static const size_t B3_OFF   = 93280;
static const size_t PXP_OFF  = 93440;          // u32 region, 12582912 + 64

__device__ inline unsigned short rneb(float x) {
    unsigned u = __float_as_uint(x);
    return (unsigned short)((u + 0x7FFFu + ((u >> 16) & 1u)) >> 16);
}
__device__ inline float b2f(unsigned short h) {
    return __uint_as_float(((unsigned)h) << 16);
}
__device__ inline unsigned packhl(float v) {
    unsigned short h = rneb(v);
    return ((unsigned)h << 16) | (unsigned)rneb(v - b2f(h));
}

// ---------------- prep: BN-fold + reorder to MFMA B-fragment layout, hi/lo split
__global__ __launch_bounds__(256) void k_prep(
    const float* __restrict__ c1w, const float* __restrict__ c2w, const float* __restrict__ c3w,
    const float* __restrict__ c1b, const float* __restrict__ g1, const float* __restrict__ be1,
    const float* __restrict__ m1, const float* __restrict__ v1,
    const float* __restrict__ c2b, const float* __restrict__ g2, const float* __restrict__ be2,
    const float* __restrict__ m2, const float* __restrict__ v2,
    const float* __restrict__ c3b, const float* __restrict__ g3, const float* __restrict__ be3,
    const float* __restrict__ m3, const float* __restrict__ v3,
    unsigned short* __restrict__ w1c2, unsigned short* __restrict__ w2c2,
    unsigned short* __restrict__ w3c2,
    float* __restrict__ b1c, float* __restrict__ b2c, float* __restrict__ b3c)
{
    int i = blockIdx.x * 256 + threadIdx.x;
    if (i < 2048) {
        int e = i & 7, p = (i >> 3) & 1, kc = (i >> 4) & 3, ol = (i >> 6) & 15, n = i >> 10;
        int o = n * 16 + ol, k = kc * 8 + e;
        float s = g1[o] * rsqrtf(v1[o] + BN_EPS);
        float wv = (k < 27) ? c1w[o * 27 + k] * s : 0.f;
        unsigned short h = rneb(wv);
        w1c2[i] = p ? rneb(wv - b2f(h)) : h;
        return;
    }
    i -= 2048;
    if (i < 36864) {
        int e = i & 7, p = (i >> 3) & 1, kc = (i >> 4) & 3, ol = (i >> 6) & 15;
        int n = (i >> 10) & 3, tap = i >> 12;
        int o = n * 16 + ol, ci = kc * 8 + e;
        float s = g2[o] * rsqrtf(v2[o] + BN_EPS);
        float wv = c2w[o * 288 + ci * 9 + tap] * s;
        unsigned short h = rneb(wv);
        w2c2[i] = p ? rneb(wv - b2f(h)) : h;
        return;
    }
    i -= 36864;
    if (i < 147456) {
        int e = i & 7, p = (i >> 3) & 1, kc = (i >> 4) & 3, ol = (i >> 6) & 15;
        int nf = (i >> 10) & 7, s_ = (i >> 13) & 1, tap = i >> 14;
        int o = nf * 16 + ol, ci = s_ * 32 + kc * 8 + e;
        float sc = g3[o] * rsqrtf(v3[o] + BN_EPS);
        float wv = c3w[o * 576 + ci * 9 + tap] * sc;
        unsigned short h = rneb(wv);
        w3c2[i] = p ? rneb(wv - b2f(h)) : h;
        return;
    }
    i -= 147456;
    if (i < 32) { float s = g1[i]*rsqrtf(v1[i]+BN_EPS); b1c[i] = (c1b[i]-m1[i])*s + be1[i]; return; }
    i -= 32;
    if (i < 64) { float s = g2[i]*rsqrtf(v2[i]+BN_EPS); b2c[i] = (c2b[i]-m2[i])*s + be2[i]; return; }
    i -= 64;
    if (i < 128) { float s = g3[i]*rsqrtf(v3[i]+BN_EPS); b3c[i] = (c3b[i]-m3[i])*s + be3[i]; return; }
}

// ---------------- pack x -> hi|lo u32 (streaming, float4-vectorized) ----------
__global__ __launch_bounds__(256) void k_packx(const float* __restrict__ x,
                                               unsigned* __restrict__ pxg)
{
    size_t gid = (size_t)blockIdx.x * 256 + threadIdx.x;   // 0..3145727
    float4 v = ((const float4*)x)[gid];
    uint4 o;
    o.x = packhl(v.x); o.y = packhl(v.y); o.z = packhl(v.z); o.w = packhl(v.w);
    ((uint4*)pxg)[gid] = o;
    if (gid < 64) pxg[12582912 + gid] = 0;                 // OOB guard
}

// ---------------- fully fused, 1 image/block, 512 thr, LDS = 41472 B ---------
// LDSU (20736 u16): conv2-in padded [py18][kc4][px18][e8], hi 0 / lo +10368
//   after P2 reads: conv3-in padded [py10][kc8][px11][e8], hi [0,7040) / lo [7040,14080)
//   dead tail u16[14080,20736): sFeat f@14080 | sPart f@14336 | sOut f@15360
// x is NOT staged: P1 gathers packed x from global (L1-resident per block).
// 41472*3 = 124416 <= 128KB effective pool -> 3 blocks/CU (theory under test).
__global__ __launch_bounds__(512) void k_fused(
    const unsigned* __restrict__ pxp,
    const unsigned short* __restrict__ w1c2,
    const unsigned short* __restrict__ w2c2,
    const unsigned short* __restrict__ w3c2,
    const float* __restrict__ b1c, const float* __restrict__ b2c, const float* __restrict__ b3c,
    const float* __restrict__ w1e, const float* __restrict__ b1e,
    const float* __restrict__ w2e, const float* __restrict__ b2e,
    const float* __restrict__ gw, const float* __restrict__ gb,
    float* __restrict__ out)
{
    __shared__ __align__(16) unsigned short LDSU[20736];
    float* sFeat = (float*)(LDSU + 14080);     // 128 f
    float* sPart = (float*)(LDSU + 14336);     // 512 f
    float* sOutB = (float*)(LDSU + 15360);     // 20 f

    const int b = blockIdx.x, t = threadIdx.x;
    const int lane = t & 63, w = t >> 6;
    const int l15 = lane & 15, lg = lane >> 4;
    const int4 z4 = {0, 0, 0, 0};

    // ---------------- P0: zero conv2-in halos (no barrier needed before P1) ---
    for (int hh = t; hh < 272; hh += 512) {        // 68 halo (py,px) x 4 kc
        int pr = hh >> 2, kc = hh & 3;
        int py, px;
        if (pr < 36) { py = (pr < 18) ? 0 : 17; px = (pr < 18) ? pr : pr - 18; }
        else { int r = pr - 36; py = 1 + (r >> 1); px = (r & 1) ? 17 : 0; }
        int ei = ((py * 4 + kc) * 18 + px) * 8;
        *(int4*)(LDSU + ei) = z4;
        *(int4*)(LDSU + 10368 + ei) = z4;
    }

    // ---------------- P1: conv1 (3->32 @32x32) via global packed-x gathers ----
    {
        short8 b1h[2], b1l[2];
#pragma unroll
        for (int n = 0; n < 2; n++) {
            const short8* bp = (const short8*)(w1c2 + 16 * ((n * 16 + l15) * 4 + lg));
            b1h[n] = bp[0]; b1l[n] = bp[1];
        }
        int dyE[8], dxE[8], cbE[8];
#pragma unroll
        for (int e = 0; e < 8; e++) {
            int k = lg * 8 + e;
            if (k < 27) { int ci = k / 9, tp = k - ci * 9;
                          dyE[e] = tp / 3 - 1; dxE[e] = tp % 3 - 1; cbE[e] = ci << 10; }
            else { dyE[e] = -1000; dxE[e] = 0; cbE[e] = 0; }
        }
        float bia[2] = { b1c[l15], b1c[16 + l15] };
        const unsigned* gxb = pxp + (size_t)b * 3072;
#pragma unroll 1
        for (int q = 0; q < 2; q++) {
            int m0 = 8 * w + 4 * q;
            f32x4 acc[4][2];
#pragma unroll
            for (int mi = 0; mi < 4; mi++)
#pragma unroll
                for (int n = 0; n < 2; n++) acc[mi][n] = (f32x4)0.f;
#pragma unroll
            for (int mi = 0; mi < 4; mi++) {
                int pos = 16 * (m0 + mi) + l15, py = pos >> 5, px = pos & 31;
                short8 ah, al;
#pragma unroll
                for (int e = 0; e < 8; e++) {
                    int yy = py + dyE[e], xv = px + dxE[e];
                    int idx = cbE[e] + (yy << 5) + xv;
                    bool ok = ((unsigned)yy < 32u) && ((unsigned)xv < 32u);
                    unsigned u = gxb[idx];             // valid mem even OOB (guard/weights)
                    u = ok ? u : 0u;
                    ah[e] = (short)(u >> 16);
                    al[e] = (short)(u & 0xFFFFu);
                }
#pragma unroll
                for (int n = 0; n < 2; n++) {
                    acc[mi][n] = MFMA(ah, b1h[n], acc[mi][n], 0, 0, 0);
                    acc[mi][n] = MFMA(ah, b1l[n], acc[mi][n], 0, 0, 0);
                    acc[mi][n] = MFMA(al, b1h[n], acc[mi][n], 0, 0, 0);
                }
            }
            int PY = 2 * w + q;
#pragma unroll
            for (int n = 0; n < 2; n++) {
                int o = n * 16 + l15;
#pragma unroll
                for (int h = 0; h < 2; h++)
#pragma unroll
                for (int jp = 0; jp < 2; jp++) {
                    float v00 = fmaxf(acc[h][n][2*jp]     + bia[n], 0.f);
                    float v01 = fmaxf(acc[h][n][2*jp + 1] + bia[n], 0.f);
                    float v10 = fmaxf(acc[h+2][n][2*jp]     + bia[n], 0.f);
                    float v11 = fmaxf(acc[h+2][n][2*jp + 1] + bia[n], 0.f);
                    float pm = fmaxf(fmaxf(v00, v01), fmaxf(v10, v11));
                    int PX = h * 8 + lg * 2 + jp;
                    unsigned short ph = rneb(pm), pl = rneb(pm - b2f(ph));
                    int ei = (((PY + 1) * 4 + (o >> 3)) * 18 + (PX + 1)) * 8 + (o & 7);
                    LDSU[ei] = ph; LDSU[10368 + ei] = pl;
                }
            }
        }
    }
    __syncthreads();

    // ---------------- P2: conv2 (32->64 @16x16), padded, N-split + B prefetch -
    {
        const int mh = w & 1, nn = w >> 1;
        f32x4 acc2[8];
#pragma unroll
        for (int mi = 0; mi < 8; mi++) acc2[mi] = (f32x4)0.f;
        const unsigned short* wb = w2c2 + ((size_t)(nn * 16 + l15) * 4 + lg) * 16;
        const int abase = (mh * 8) * 576 + lg * 144 + l15 * 8;
        short8 bhA, blA, bhB, blB;
#define LDB2(tp, BH, BL) { const short8* bp = (const short8*)(wb + (tp) * 4096); BH = bp[0]; BL = bp[1]; }
#define CMP2(tp, BH, BL) { int dy_ = (tp) / 3, dx_ = (tp) - 3 * dy_; \
        int roff_ = dy_ * 576 + dx_ * 8; \
        _Pragma("unroll") for (int mi = 0; mi < 8; mi++) { \
            int ea_ = abase + mi * 576 + roff_; \
            short8 ah_ = *(const short8*)(LDSU + ea_); \
            short8 al_ = *(const short8*)(LDSU + 10368 + ea_); \
            acc2[mi] = MFMA(ah_, BH, acc2[mi], 0, 0, 0); \
            acc2[mi] = MFMA(ah_, BL, acc2[mi], 0, 0, 0); \
            acc2[mi] = MFMA(al_, BH, acc2[mi], 0, 0, 0); } }
        LDB2(0, bhA, blA);
#pragma unroll 1
        for (int tp = 0; tp < 8; tp += 2) {
            LDB2(tp + 1, bhB, blB);
            CMP2(tp, bhA, blA);
            LDB2(tp + 2, bhA, blA);
            CMP2(tp + 1, bhB, blB);
        }
        CMP2(8, bhA, blA);
        __syncthreads();                 // all conv2 reads retired
        // conv3-in halo zeros [py10][kc8][px11][e8]
        for (int hh = t; hh < 288; hh += 512) {     // 36 halo (py,px) x 8 kc
            int pr = hh >> 3, kc = hh & 7;
            int py, px;
            if (pr < 20) { py = (pr < 10) ? 0 : 9; px = (pr < 10) ? pr : pr - 10; }
            else { int r = pr - 20; py = 1 + (r >> 1); px = (r & 1) ? 9 : 0; }
            int ei = ((py * 8 + kc) * 11 + px) * 8;
            *(int4*)(LDSU + ei) = z4;
            *(int4*)(LDSU + 7040 + ei) = z4;
        }
        // epilogue: relu + 2x2 maxpool -> conv3-in payload
        {
            int o = nn * 16 + l15;
            float bia = b2c[o];
#pragma unroll
            for (int mi2 = 0; mi2 < 4; mi2++) {
                int PY = mh * 4 + mi2;
#pragma unroll
                for (int jp = 0; jp < 2; jp++) {
                    float v00 = fmaxf(acc2[2*mi2][2*jp]     + bia, 0.f);
                    float v01 = fmaxf(acc2[2*mi2][2*jp + 1] + bia, 0.f);
                    float v10 = fmaxf(acc2[2*mi2+1][2*jp]     + bia, 0.f);
                    float v11 = fmaxf(acc2[2*mi2+1][2*jp + 1] + bia, 0.f);
                    float pm = fmaxf(fmaxf(v00, v01), fmaxf(v10, v11));
                    int PX = lg * 2 + jp;
                    unsigned short ph = rneb(pm), pl = rneb(pm - b2f(ph));
                    int ei = (((PY + 1) * 8 + (o >> 3)) * 11 + (PX + 1)) * 8 + (o & 7);
                    LDSU[ei] = ph; LDSU[7040 + ei] = pl;
                }
            }
        }
    }
    __syncthreads();

    // ---------------- P3: conv3 (64->128 @8x8), padded, wave-per-nf -----------
    {
        const int nf = w;
        f32x4 acc3[4];
#pragma unroll
        for (int mi = 0; mi < 4; mi++) acc3[mi] = (f32x4)0.f;
        const unsigned short* wb3 = w3c2 + ((size_t)(nf * 16 + l15) * 4 + lg) * 16;
        const int py0 = (l15 >> 3), px3 = l15 & 7;
        short8 bhA, blA, bhB, blB;
#define LDB3(ii, BH, BL) { const short8* bp = (const short8*)(wb3 + (ii) * 8192); BH = bp[0]; BL = bp[1]; }
#define CMP3(ii, BH, BL) { int tap_ = (ii) >> 1, s_ = (ii) & 1; \
        int dy_ = tap_ / 3, dx_ = tap_ - 3 * dy_; \
        int roff_ = dy_ * 704 + (s_ * 4 + lg) * 88 + dx_ * 8 + px3 * 8; \
        _Pragma("unroll") for (int mi = 0; mi < 4; mi++) { \
            int ea_ = (mi * 2 + py0) * 704 + roff_; \
            short8 ah_ = *(const short8*)(LDSU + ea_); \
            short8 al_ = *(const short8*)(LDSU + 7040 + ea_); \
            acc3[mi] = MFMA(ah_, BH, acc3[mi], 0, 0, 0); \
            acc3[mi] = MFMA(ah_, BL, acc3[mi], 0, 0, 0); \
            acc3[mi] = MFMA(al_, BH, acc3[mi], 0, 0, 0); } }
        LDB3(0, bhA, blA);
#pragma unroll 1
        for (int ii = 0; ii < 16; ii += 2) {
            LDB3(ii + 1, bhB, blB);
            CMP3(ii, bhA, blA);
            LDB3(ii + 2, bhA, blA);
            CMP3(ii + 1, bhB, blB);
        }
        LDB3(17, bhB, blB);
        CMP3(16, bhA, blA);
        CMP3(17, bhB, blB);
        // epilogue: relu + 2x2 maxpool + avg -> sFeat (dead-tail region)
        {
            int o = nf * 16 + l15;
            float bia = b3c[o];
            float featsum = 0.f;
#pragma unroll
            for (int mi = 0; mi < 4; mi++) {
                float sumv = 0.f;
#pragma unroll
                for (int jp = 0; jp < 2; jp++) {
                    float v0 = fmaxf(acc3[mi][2*jp]     + bia, 0.f);
                    float v1 = fmaxf(acc3[mi][2*jp + 1] + bia, 0.f);
                    float vm = fmaxf(v0, v1);
                    vm = fmaxf(vm, __shfl_xor(vm, 32, 64));   // py-pair
                    sumv += vm;
                }
                sumv += __shfl_xor(sumv, 16, 64);             // px halves
                featsum += sumv;
            }
            if (lane < 16) sFeat[nf * 16 + lane] = featsum * (1.0f / 16.0f);
        }
    }
    __syncthreads();

    // ---------------- P4: gate top-2 (all waves) + split expert MLPs ----------
    int i1 = 0, i2 = 0;
    float wk1 = 0.f, wk2 = 0.f;
    {
        float f0 = sFeat[lane], f1 = sFeat[64 + lane];
        float lgt[8];
#pragma unroll
        for (int e = 0; e < 8; e++) {
            float p = f0 * gw[lane * 8 + e] + f1 * gw[(64 + lane) * 8 + e];
#pragma unroll
            for (int s = 1; s < 64; s <<= 1) p += __shfl_xor(p, s, 64);
            lgt[e] = p + gb[e];
        }
        float v1m = -1e30f, v2m = -1e30f;
#pragma unroll
        for (int e = 0; e < 8; e++) {
            float le = lgt[e];
            if (le > v1m) { v2m = v1m; i2 = i1; v1m = le; i1 = e; }
            else if (le > v2m) { v2m = le; i2 = e; }
        }
        float ex = expf(v2m - v1m);
        wk1 = 1.f / (1.f + ex); wk2 = ex / (1.f + ex);
        int e = (w < 4) ? i1 : i2;
        int k0 = (w & 3) * 32;
        const float* W1 = w1e + (size_t)e * 8192 + (size_t)k0 * 64;
        float hj = 0.f;
#pragma unroll 8
        for (int kk = 0; kk < 32; kk++) hj += sFeat[k0 + kk] * W1[kk * 64 + lane];
        sPart[w * 64 + lane] = hj;
    }
    __syncthreads();
    if (w < 2) {
        int e = (w == 0) ? i1 : i2;
        float wk = (w == 0) ? wk1 : wk2;
        float hj = b1e[e * 64 + lane]
                 + sPart[(w * 4 + 0) * 64 + lane] + sPart[(w * 4 + 1) * 64 + lane]
                 + sPart[(w * 4 + 2) * 64 + lane] + sPart[(w * 4 + 3) * 64 + lane];
        hj = fmaxf(hj, 0.f);
        const float* W2 = w2e + (size_t)e * 640 + lane * 10;
#pragma unroll
        for (int o = 0; o < 10; o++) {
            float po = hj * W2[o];
#pragma unroll
            for (int s = 1; s < 64; s <<= 1) po += __shfl_xor(po, s, 64);
            if (lane == 0) sOutB[w * 10 + o] = wk * (po + b2e[e * 10 + o]);
        }
    }
    __syncthreads();
    if (t < 10) out[(size_t)b * 10 + t] = sOutB[t] + sOutB[10 + t];
}

extern "C" void kernel_launch(void* const* d_in, const int* in_sizes, int n_in,
                              void* d_out, int out_size, void* d_ws, size_t ws_size,
                              hipStream_t stream)
{
    const float* x   = (const float*)d_in[0];
    const float* c1w = (const float*)d_in[1];
    const float* c1b = (const float*)d_in[2];
    const float* g1  = (const float*)d_in[3];
    const float* be1 = (const float*)d_in[4];
    const float* m1  = (const float*)d_in[5];
    const float* v1  = (const float*)d_in[6];
    const float* c2w = (const float*)d_in[7];
    const float* c2b = (const float*)d_in[8];
    const float* g2  = (const float*)d_in[9];
    const float* be2 = (const float*)d_in[10];
    const float* m2  = (const float*)d_in[11];
    const float* v2  = (const float*)d_in[12];
    const float* c3w = (const float*)d_in[13];
    const float* c3b = (const float*)d_in[14];
    const float* g3  = (const float*)d_in[15];
    const float* be3 = (const float*)d_in[16];
    const float* m3  = (const float*)d_in[17];
    const float* v3  = (const float*)d_in[18];
    const float* w1e = (const float*)d_in[19];
    const float* b1e = (const float*)d_in[20];
    const float* w2e = (const float*)d_in[21];
    const float* b2e = (const float*)d_in[22];
    const float* gw  = (const float*)d_in[23];
    const float* gb  = (const float*)d_in[24];

    float* ws = (float*)d_ws;
    unsigned short* w1c2 = (unsigned short*)(ws + W1C2_OFF);
    unsigned short* w2c2 = (unsigned short*)(ws + W2C2_OFF);
    unsigned short* w3c2 = (unsigned short*)(ws + W3C2_OFF);
    float* b1c = ws + B1_OFF;
    float* b2c = ws + B2_OFF;
    float* b3c = ws + B3_OFF;
    unsigned* pxp = (unsigned*)(ws + PXP_OFF);

    k_prep<<<729, 256, 0, stream>>>(c1w, c2w, c3w,
                                    c1b, g1, be1, m1, v1,
                                    c2b, g2, be2, m2, v2,
                                    c3b, g3, be3, m3, v3,
                                    w1c2, w2c2, w3c2, b1c, b2c, b3c);
    k_packx<<<12288, 256, 0, stream>>>(x, pxp);
    k_fused<<<4096, 512, 0, stream>>>(pxp, w1c2, w2c2, w3c2, b1c, b2c, b3c,
                                      w1e, b1e, w2e, b2e, gw, gb, (float*)d_out);
}

// Round 9
// 324.680 us; speedup vs baseline: 1.0087x; 1.0087x over previous
//
#include <hip/hip_runtime.h>
#include <math.h>

typedef __attribute__((ext_vector_type(8))) short short8;
typedef __attribute__((ext_vector_type(4))) float f32x4;
#define MFMA __builtin_amdgcn_mfma_f32_16x16x32_bf16

#define BN_EPS 1e-5f

// ---------------- workspace layout (float offsets) ----------------
// w1c2: 2048 u16   [n2][ol16][kc4][p2][e8]   (k>=27 zeroed -> P1 garbage-A safe)
// w2c2: 36864 u16  [tap9][n4][ol16][kc4][p2][e8]
// w3c2: 147456 u16 [tap9][s2][nf8][ol16][kc4][p2][e8]
static const size_t W1C2_OFF = 0;
static const size_t W2C2_OFF = 1024;
static const size_t W3C2_OFF = 19456;
static const size_t B1_OFF   = 93184;
static const size_t B2_OFF   = 93216;
static const size_t B3_OFF   = 93280;

__device__ inline unsigned short rneb(float x) {
    unsigned u = __float_as_uint(x);
    return (unsigned short)((u + 0x7FFFu + ((u >> 16) & 1u)) >> 16);
}
__device__ inline float b2f(unsigned short h) {
    return __uint_as_float(((unsigned)h) << 16);
}
__device__ inline unsigned packhl(float v) {
    unsigned short h = rneb(v);
    return ((unsigned)h << 16) | (unsigned)rneb(v - b2f(h));
}

// ---------------- prep: BN-fold + reorder to MFMA B-fragment layout, hi/lo split
__global__ __launch_bounds__(256) void k_prep(
    const float* __restrict__ c1w, const float* __restrict__ c2w, const float* __restrict__ c3w,
    const float* __restrict__ c1b, const float* __restrict__ g1, const float* __restrict__ be1,
    const float* __restrict__ m1, const float* __restrict__ v1,
    const float* __restrict__ c2b, const float* __restrict__ g2, const float* __restrict__ be2,
    const float* __restrict__ m2, const float* __restrict__ v2,
    const float* __restrict__ c3b, const float* __restrict__ g3, const float* __restrict__ be3,
    const float* __restrict__ m3, const float* __restrict__ v3,
    unsigned short* __restrict__ w1c2, unsigned short* __restrict__ w2c2,
    unsigned short* __restrict__ w3c2,
    float* __restrict__ b1c, float* __restrict__ b2c, float* __restrict__ b3c)
{
    int i = blockIdx.x * 256 + threadIdx.x;
    if (i < 2048) {
        int e = i & 7, p = (i >> 3) & 1, kc = (i >> 4) & 3, ol = (i >> 6) & 15, n = i >> 10;
        int o = n * 16 + ol, k = kc * 8 + e;
        float s = g1[o] * rsqrtf(v1[o] + BN_EPS);
        float wv = (k < 27) ? c1w[o * 27 + k] * s : 0.f;
        unsigned short h = rneb(wv);
        w1c2[i] = p ? rneb(wv - b2f(h)) : h;
        return;
    }
    i -= 2048;
    if (i < 36864) {
        int e = i & 7, p = (i >> 3) & 1, kc = (i >> 4) & 3, ol = (i >> 6) & 15;
        int n = (i >> 10) & 3, tap = i >> 12;
        int o = n * 16 + ol, ci = kc * 8 + e;
        float s = g2[o] * rsqrtf(v2[o] + BN_EPS);
        float wv = c2w[o * 288 + ci * 9 + tap] * s;
        unsigned short h = rneb(wv);
        w2c2[i] = p ? rneb(wv - b2f(h)) : h;
        return;
    }
    i -= 36864;
    if (i < 147456) {
        int e = i & 7, p = (i >> 3) & 1, kc = (i >> 4) & 3, ol = (i >> 6) & 15;
        int nf = (i >> 10) & 7, s_ = (i >> 13) & 1, tap = i >> 14;
        int o = nf * 16 + ol, ci = s_ * 32 + kc * 8 + e;
        float sc = g3[o] * rsqrtf(v3[o] + BN_EPS);
        float wv = c3w[o * 576 + ci * 9 + tap] * sc;
        unsigned short h = rneb(wv);
        w3c2[i] = p ? rneb(wv - b2f(h)) : h;
        return;
    }
    i -= 147456;
    if (i < 32) { float s = g1[i]*rsqrtf(v1[i]+BN_EPS); b1c[i] = (c1b[i]-m1[i])*s + be1[i]; return; }
    i -= 32;
    if (i < 64) { float s = g2[i]*rsqrtf(v2[i]+BN_EPS); b2c[i] = (c2b[i]-m2[i])*s + be2[i]; return; }
    i -= 64;
    if (i < 128) { float s = g3[i]*rsqrtf(v3[i]+BN_EPS); b3c[i] = (c3b[i]-m3[i])*s + be3[i]; return; }
}

// ---------------- fully fused, 1 image/block, 512 thr, LDS = 50736 B ---------
// LDSU u16[25368]:
//   conv2-in [py16][kc4][px18][e8] col-padded: hi u16[0,9216), lo [9216,18432)
//     after P2 reads retire -> conv3-in [py10][kc8][px11][e8]: hi [0,7040), lo [7040,14080)
//   x region: u32 xs[3468] at u16 18432: halo-padded packed x [3][34][34] (hi<<16|lo)
//     after P1 -> sFeat f[0,128) | sPart f[128,640) | sOut f[640,660) (float view of xs)
// Register discipline: peak VGPR+AGPR target <= 80 (P1/P2 acc split to 16 AGPRs)
// so 6 waves/SIMD -> 3 blocks/CU. launch_bounds(512,6) caps alloc at 85.
__global__ __launch_bounds__(512, 6) void k_fused(
    const float* __restrict__ x,
    const unsigned short* __restrict__ w1c2,
    const unsigned short* __restrict__ w2c2,
    const unsigned short* __restrict__ w3c2,
    const float* __restrict__ b1c, const float* __restrict__ b2c, const float* __restrict__ b3c,
    const float* __restrict__ w1e, const float* __restrict__ b1e,
    const float* __restrict__ w2e, const float* __restrict__ b2e,
    const float* __restrict__ gw, const float* __restrict__ gb,
    float* __restrict__ out)
{
    __shared__ __align__(16) unsigned short LDSU[25368];
    unsigned* xs = (unsigned*)(LDSU + 18432);      // 3468 u32
    float* sFeat = (float*)xs;                     // [0,128)
    float* sPart = (float*)xs + 128;               // [128,640)
    float* sOutB = (float*)xs + 640;               // [640,660)

    const int b = blockIdx.x, t = threadIdx.x;
    const int lane = t & 63, w = t >> 6;
    const int l15 = lane & 15, lg = lane >> 4;
    const int4 z4 = {0, 0, 0, 0};

    // ---------------- P0: stage halo'd packed x + zero halos ----------------
    {
        const float* xb = x + (size_t)b * 3072;
        for (int i = t; i < 3072; i += 512) {
            int ci = i >> 10, y = (i >> 5) & 31, xx = i & 31;
            xs[ci * 1156 + (y + 1) * 34 + (xx + 1)] = packhl(xb[i]);
        }
        for (int hh = t; hh < 396; hh += 512) {        // x halo (132 per channel)
            int ci = (hh * 31776) >> 22;
            int r = hh - ci * 132;
            int yy, xx;
            if (r < 68) { yy = (r < 34) ? 0 : 33; xx = (r < 34) ? r : r - 34; }
            else { int rr = r - 68; yy = 1 + (rr >> 1); xx = (rr & 1) ? 33 : 0; }
            xs[ci * 1156 + yy * 34 + xx] = 0u;
        }
        for (int hh = t; hh < 128; hh += 512) {        // conv2-in px-halo cols 0,17
            int py = hh >> 3, kc = (hh >> 1) & 3, px = (hh & 1) ? 17 : 0;
            int ei = ((py * 4 + kc) * 18 + px) * 8;
            *(int4*)(LDSU + ei) = z4;
            *(int4*)(LDSU + 9216 + ei) = z4;
        }
    }
    __syncthreads();

    // ---------------- P1: conv1 (3->32 @32x32), mi-split (16 AGPR) ------------
    {
        short8 b1h[2], b1l[2];
#pragma unroll
        for (int n = 0; n < 2; n++) {
            const short8* bp = (const short8*)(w1c2 + 16 * ((n * 16 + l15) * 4 + lg));
            b1h[n] = bp[0]; b1l[n] = bp[1];
        }
        int aoffU[8];
#pragma unroll
        for (int e = 0; e < 8; e++) {
            int k = lg * 8 + e;
            if (k < 27) { int ci = k / 9, tp = k - ci * 9;
                          aoffU[e] = ci * 1156 + (tp / 3) * 34 + (tp % 3); }
            else aoffU[e] = 0;     // B-weight is zero for k>=27: A may be garbage
        }
        float bia[2] = { b1c[l15], b1c[16 + l15] };
#pragma unroll 1
        for (int q = 0; q < 2; q++) {
#pragma unroll 1
            for (int pp = 0; pp < 2; pp++) {
                int m0 = 8 * w + 4 * q;
                f32x4 acc[2][2];
#pragma unroll
                for (int ii = 0; ii < 2; ii++)
#pragma unroll
                    for (int n = 0; n < 2; n++) acc[ii][n] = (f32x4)0.f;
#pragma unroll
                for (int ii = 0; ii < 2; ii++) {
                    int mi = pp + 2 * ii;
                    int pos = 16 * (m0 + mi) + l15, py = pos >> 5, px = pos & 31;
                    int base = py * 34 + px;
                    short8 ah, al;
#pragma unroll
                    for (int e = 0; e < 8; e++) {
                        unsigned u = xs[base + aoffU[e]];
                        ah[e] = (short)(u >> 16);
                        al[e] = (short)(u & 0xFFFFu);
                    }
#pragma unroll
                    for (int n = 0; n < 2; n++) {
                        acc[ii][n] = MFMA(ah, b1h[n], acc[ii][n], 0, 0, 0);
                        acc[ii][n] = MFMA(ah, b1l[n], acc[ii][n], 0, 0, 0);
                        acc[ii][n] = MFMA(al, b1h[n], acc[ii][n], 0, 0, 0);
                    }
                }
                int PY = 2 * w + q;
#pragma unroll
                for (int n = 0; n < 2; n++) {
                    int o = n * 16 + l15;
#pragma unroll
                    for (int jp = 0; jp < 2; jp++) {
                        float v00 = fmaxf(acc[0][n][2*jp]     + bia[n], 0.f);
                        float v01 = fmaxf(acc[0][n][2*jp + 1] + bia[n], 0.f);
                        float v10 = fmaxf(acc[1][n][2*jp]     + bia[n], 0.f);
                        float v11 = fmaxf(acc[1][n][2*jp + 1] + bia[n], 0.f);
                        float pm = fmaxf(fmaxf(v00, v01), fmaxf(v10, v11));
                        int PX = pp * 8 + lg * 2 + jp;
                        int ei = ((PY * 4 + (o >> 3)) * 18 + (PX + 1)) * 8 + (o & 7);
                        unsigned short ph = rneb(pm);
                        LDSU[ei] = ph;
                        LDSU[9216 + ei] = rneb(pm - b2f(ph));
                    }
                }
            }
        }
    }
    __syncthreads();

    // ---------------- P2: conv2 (32->64 @16x16), mp-split (16 AGPR) -----------
    {
        const int mh = w & 1, nn = w >> 1;
        const unsigned short* wb = w2c2 + ((size_t)(nn * 16 + l15) * 4 + lg) * 16;
        float pmv0[4], pmv1[4];
        short8 bhA, blA, bhB, blB;
#define LDB2(tp, BH, BL) { const short8* bp = (const short8*)(wb + (tp) * 4096); BH = bp[0]; BL = bp[1]; }
#define CMP2(tp, BH, BL, ACC, MP) { int dy_ = (tp) / 3, dx_ = (tp) - 3 * dy_; \
        _Pragma("unroll") for (int mii = 0; mii < 4; mii++) { \
            int py1_ = mh * 8 + (MP) * 4 + mii + dy_ - 1; \
            if ((unsigned)py1_ < 16u) { \
                int ea_ = py1_ * 576 + lg * 144 + (l15 + dx_) * 8; \
                short8 ah_ = *(const short8*)(LDSU + ea_); \
                short8 al_ = *(const short8*)(LDSU + 9216 + ea_); \
                ACC[mii] = MFMA(ah_, BH, ACC[mii], 0, 0, 0); \
                ACC[mii] = MFMA(ah_, BL, ACC[mii], 0, 0, 0); \
                ACC[mii] = MFMA(al_, BH, ACC[mii], 0, 0, 0); } } }
#define P2PASS(MP, PMV) { \
        f32x4 acc2[4]; \
        _Pragma("unroll") for (int mi = 0; mi < 4; mi++) acc2[mi] = (f32x4)0.f; \
        LDB2(0, bhA, blA); \
        _Pragma("unroll 1") for (int tp = 0; tp < 8; tp += 2) { \
            LDB2(tp + 1, bhB, blB); \
            CMP2(tp, bhA, blA, acc2, MP); \
            LDB2(tp + 2, bhA, blA); \
            CMP2(tp + 1, bhB, blB, acc2, MP); \
        } \
        CMP2(8, bhA, blA, acc2, MP); \
        { float bia_ = b2c[nn * 16 + l15]; \
          _Pragma("unroll") for (int r = 0; r < 2; r++) \
          _Pragma("unroll") for (int jp = 0; jp < 2; jp++) { \
            float v00 = fmaxf(acc2[2*r][2*jp]     + bia_, 0.f); \
            float v01 = fmaxf(acc2[2*r][2*jp + 1] + bia_, 0.f); \
            float v10 = fmaxf(acc2[2*r+1][2*jp]     + bia_, 0.f); \
            float v11 = fmaxf(acc2[2*r+1][2*jp + 1] + bia_, 0.f); \
            PMV[r * 2 + jp] = fmaxf(fmaxf(v00, v01), fmaxf(v10, v11)); } } }
        P2PASS(0, pmv0);
        P2PASS(1, pmv1);
        __syncthreads();                 // all conv2-in reads retired
        // conv3-in halo zeros [py10][kc8][px11][e8]
        for (int hh = t; hh < 288; hh += 512) {     // 36 halo (py,px) x 8 kc
            int pr = hh >> 3, kc = hh & 7;
            int py, px;
            if (pr < 20) { py = (pr < 10) ? 0 : 9; px = (pr < 10) ? pr : pr - 10; }
            else { int r = pr - 20; py = 1 + (r >> 1); px = (r & 1) ? 9 : 0; }
            int ei = ((py * 8 + kc) * 11 + px) * 8;
            *(int4*)(LDSU + ei) = z4;
            *(int4*)(LDSU + 7040 + ei) = z4;
        }
        // payload writes (both passes)
        {
            int o = nn * 16 + l15;
#pragma unroll
            for (int mp = 0; mp < 2; mp++)
#pragma unroll
            for (int r = 0; r < 2; r++)
#pragma unroll
            for (int jp = 0; jp < 2; jp++) {
                float pm = (mp == 0) ? pmv0[r * 2 + jp] : pmv1[r * 2 + jp];
                int PY = mh * 4 + mp * 2 + r;
                int PX = lg * 2 + jp;
                int ei = (((PY + 1) * 8 + (o >> 3)) * 11 + (PX + 1)) * 8 + (o & 7);
                unsigned short ph = rneb(pm);
                LDSU[ei] = ph;
                LDSU[7040 + ei] = rneb(pm - b2f(ph));
            }
        }
    }
    __syncthreads();

    // ---------------- P3: conv3 (64->128 @8x8), wave-per-nf + B prefetch ------
    {
        const int nf = w;
        f32x4 acc3[4];
#pragma unroll
        for (int mi = 0; mi < 4; mi++) acc3[mi] = (f32x4)0.f;
        const unsigned short* wb3 = w3c2 + ((size_t)(nf * 16 + l15) * 4 + lg) * 16;
        const int py0 = (l15 >> 3), px3 = l15 & 7;
        short8 bhA, blA, bhB, blB;
#define LDB3(ii, BH, BL) { const short8* bp = (const short8*)(wb3 + (ii) * 8192); BH = bp[0]; BL = bp[1]; }
#define CMP3(ii, BH, BL) { int tap_ = (ii) >> 1, s_ = (ii) & 1; \
        int dy_ = tap_ / 3, dx_ = tap_ - 3 * dy_; \
        int roff_ = dy_ * 704 + (s_ * 4 + lg) * 88 + dx_ * 8 + px3 * 8; \
        _Pragma("unroll") for (int mi = 0; mi < 4; mi++) { \
            int ea_ = (mi * 2 + py0) * 704 + roff_; \
            short8 ah_ = *(const short8*)(LDSU + ea_); \
            short8 al_ = *(const short8*)(LDSU + 7040 + ea_); \
            acc3[mi] = MFMA(ah_, BH, acc3[mi], 0, 0, 0); \
            acc3[mi] = MFMA(ah_, BL, acc3[mi], 0, 0, 0); \
            acc3[mi] = MFMA(al_, BH, acc3[mi], 0, 0, 0); } }
        LDB3(0, bhA, blA);
#pragma unroll 1
        for (int ii = 0; ii < 16; ii += 2) {
            LDB3(ii + 1, bhB, blB);
            CMP3(ii, bhA, blA);
            LDB3(ii + 2, bhA, blA);
            CMP3(ii + 1, bhB, blB);
        }
        LDB3(17, bhB, blB);
        CMP3(16, bhA, blA);
        CMP3(17, bhB, blB);
        // epilogue: relu + 2x2 maxpool + avg -> sFeat (x region, dead)
        {
            int o = nf * 16 + l15;
            float bia = b3c[o];
            float featsum = 0.f;
#pragma unroll
            for (int mi = 0; mi < 4; mi++) {
                float sumv = 0.f;
#pragma unroll
                for (int jp = 0; jp < 2; jp++) {
                    float v0 = fmaxf(acc3[mi][2*jp]     + bia, 0.f);
                    float v1 = fmaxf(acc3[mi][2*jp + 1] + bia, 0.f);
                    float vm = fmaxf(v0, v1);
                    vm = fmaxf(vm, __shfl_xor(vm, 32, 64));   // py-pair
                    sumv += vm;
                }
                sumv += __shfl_xor(sumv, 16, 64);             // px halves
                featsum += sumv;
            }
            if (lane < 16) sFeat[nf * 16 + lane] = featsum * (1.0f / 16.0f);
        }
    }
    __syncthreads();

    // ---------------- P4: gate top-2 (all waves) + split expert MLPs ----------
    int i1 = 0, i2 = 0;
    float wk1 = 0.f, wk2 = 0.f;
    {
        float f0 = sFeat[lane], f1 = sFeat[64 + lane];
        float lgt[8];
#pragma unroll
        for (int e = 0; e < 8; e++) {
            float p = f0 * gw[lane * 8 + e] + f1 * gw[(64 + lane) * 8 + e];
#pragma unroll
            for (int s = 1; s < 64; s <<= 1) p += __shfl_xor(p, s, 64);
            lgt[e] = p + gb[e];
        }
        float v1m = -1e30f, v2m = -1e30f;
#pragma unroll
        for (int e = 0; e < 8; e++) {
            float le = lgt[e];
            if (le > v1m) { v2m = v1m; i2 = i1; v1m = le; i1 = e; }
            else if (le > v2m) { v2m = le; i2 = e; }
        }
        float ex = expf(v2m - v1m);
        wk1 = 1.f / (1.f + ex); wk2 = ex / (1.f + ex);
        int e = (w < 4) ? i1 : i2;
        int k0 = (w & 3) * 32;
        const float* W1 = w1e + (size_t)e * 8192 + (size_t)k0 * 64;
        float hj = 0.f;
#pragma unroll 8
        for (int kk = 0; kk < 32; kk++) hj += sFeat[k0 + kk] * W1[kk * 64 + lane];
        sPart[w * 64 + lane] = hj;
    }
    __syncthreads();
    if (w < 2) {
        int e = (w == 0) ? i1 : i2;
        float wk = (w == 0) ? wk1 : wk2;
        float hj = b1e[e * 64 + lane]
                 + sPart[(w * 4 + 0) * 64 + lane] + sPart[(w * 4 + 1) * 64 + lane]
                 + sPart[(w * 4 + 2) * 64 + lane] + sPart[(w * 4 + 3) * 64 + lane];
        hj = fmaxf(hj, 0.f);
        const float* W2 = w2e + (size_t)e * 640 + lane * 10;
#pragma unroll
        for (int o = 0; o < 10; o++) {
            float po = hj * W2[o];
#pragma unroll
            for (int s = 1; s < 64; s <<= 1) po += __shfl_xor(po, s, 64);
            if (lane == 0) sOutB[w * 10 + o] = wk * (po + b2e[e * 10 + o]);
        }
    }
    __syncthreads();
    if (t < 10) out[(size_t)b * 10 + t] = sOutB[t] + sOutB[10 + t];
}

extern "C" void kernel_launch(void* const* d_in, const int* in_sizes, int n_in,
                              void* d_out, int out_size, void* d_ws, size_t ws_size,
                              hipStream_t stream)
{
    const float* x   = (const float*)d_in[0];
    const float* c1w = (const float*)d_in[1];
    const float* c1b = (const float*)d_in[2];
    const float* g1  = (const float*)d_in[3];
    const float* be1 = (const float*)d_in[4];
    const float* m1  = (const float*)d_in[5];
    const float* v1  = (const float*)d_in[6];
    const float* c2w = (const float*)d_in[7];
    const float* c2b = (const float*)d_in[8];
    const float* g2  = (const float*)d_in[9];
    const float* be2 = (const float*)d_in[10];
    const float* m2  = (const float*)d_in[11];
    const float* v2  = (const float*)d_in[12];
    const float* c3w = (const float*)d_in[13];
    const float* c3b = (const float*)d_in[14];
    const float* g3  = (const float*)d_in[15];
    const float* be3 = (const float*)d_in[16];
    const float* m3  = (const float*)d_in[17];
    const float* v3  = (const float*)d_in[18];
    const float* w1e = (const float*)d_in[19];
    const float* b1e = (const float*)d_in[20];
    const float* w2e = (const float*)d_in[21];
    const float* b2e = (const float*)d_in[22];
    const float* gw  = (const float*)d_in[23];
    const float* gb  = (const float*)d_in[24];

    float* ws = (float*)d_ws;
    unsigned short* w1c2 = (unsigned short*)(ws + W1C2_OFF);
    unsigned short* w2c2 = (unsigned short*)(ws + W2C2_OFF);
    unsigned short* w3c2 = (unsigned short*)(ws + W3C2_OFF);
    float* b1c = ws + B1_OFF;
    float* b2c = ws + B2_OFF;
    float* b3c = ws + B3_OFF;

    k_prep<<<729, 256, 0, stream>>>(c1w, c2w, c3w,
                                    c1b, g1, be1, m1, v1,
                                    c2b, g2, be2, m2, v2,
                                    c3b, g3, be3, m3, v3,
                                    w1c2, w2c2, w3c2, b1c, b2c, b3c);
    k_fused<<<4096, 512, 0, stream>>>(x, w1c2, w2c2, w3c2, b1c, b2c, b3c,
                                      w1e, b1e, w2e, b2e, gw, gb, (float*)d_out);
}

// Round 10
// 304.925 us; speedup vs baseline: 1.0740x; 1.0648x over previous
//
#include <hip/hip_runtime.h>
#include <math.h>

typedef __attribute__((ext_vector_type(8))) short short8;
typedef __attribute__((ext_vector_type(4))) float f32x4;
typedef __attribute__((ext_vector_type(16))) float f32x16;
#define MFMA16 __builtin_amdgcn_mfma_f32_16x16x32_bf16
#define MFMA32 __builtin_amdgcn_mfma_f32_32x32x16_bf16

#define BN_EPS 1e-5f

// ---------------- workspace layout (float offsets) ----------------
// w1c2: 2048 u16   [n2][ol16][kc4][p2][e8]            (16x16x32 B layout, P1)
// w2c2: 36864 u16  [tap9][ks2][nt2][col32][kh2][p2][e8] (32x32x16 B layout, P2)
// w3c2: 147456 u16 [tap9][ks4][nf4][col32][kh2][p2][e8] (32x32x16 B layout, P3)
static const size_t W1C2_OFF = 0;
static const size_t W2C2_OFF = 1024;
static const size_t W3C2_OFF = 19456;
static const size_t B1_OFF   = 93184;
static const size_t B2_OFF   = 93216;
static const size_t B3_OFF   = 93280;

__device__ inline unsigned short rneb(float x) {
    unsigned u = __float_as_uint(x);
    return (unsigned short)((u + 0x7FFFu + ((u >> 16) & 1u)) >> 16);
}
__device__ inline float b2f(unsigned short h) {
    return __uint_as_float(((unsigned)h) << 16);
}

// ---------------- prep: BN-fold + reorder to MFMA B-fragment layouts ----------
__global__ __launch_bounds__(256) void k_prep(
    const float* __restrict__ c1w, const float* __restrict__ c2w, const float* __restrict__ c3w,
    const float* __restrict__ c1b, const float* __restrict__ g1, const float* __restrict__ be1,
    const float* __restrict__ m1, const float* __restrict__ v1,
    const float* __restrict__ c2b, const float* __restrict__ g2, const float* __restrict__ be2,
    const float* __restrict__ m2, const float* __restrict__ v2,
    const float* __restrict__ c3b, const float* __restrict__ g3, const float* __restrict__ be3,
    const float* __restrict__ m3, const float* __restrict__ v3,
    unsigned short* __restrict__ w1c2, unsigned short* __restrict__ w2c2,
    unsigned short* __restrict__ w3c2,
    float* __restrict__ b1c, float* __restrict__ b2c, float* __restrict__ b3c)
{
    int i = blockIdx.x * 256 + threadIdx.x;
    if (i < 2048) {                      // P1 weights: 16x16x32 layout (unchanged)
        int e = i & 7, p = (i >> 3) & 1, kc = (i >> 4) & 3, ol = (i >> 6) & 15, n = i >> 10;
        int o = n * 16 + ol, k = kc * 8 + e;
        float s = g1[o] * rsqrtf(v1[o] + BN_EPS);
        float wv = (k < 27) ? c1w[o * 27 + k] * s : 0.f;
        unsigned short h = rneb(wv);
        w1c2[i] = p ? rneb(wv - b2f(h)) : h;
        return;
    }
    i -= 2048;
    if (i < 36864) {                     // P2 weights: 32x32x16 B layout
        int e = i & 7, p = (i >> 3) & 1, kh = (i >> 4) & 1, col = (i >> 5) & 31;
        int nt = (i >> 10) & 1, ks = (i >> 11) & 1, tap = i >> 12;
        int o = nt * 32 + col, ci = ks * 16 + kh * 8 + e;
        float s = g2[o] * rsqrtf(v2[o] + BN_EPS);
        float wv = c2w[o * 288 + ci * 9 + tap] * s;
        unsigned short h = rneb(wv);
        w2c2[i] = p ? rneb(wv - b2f(h)) : h;
        return;
    }
    i -= 36864;
    if (i < 147456) {                    // P3 weights: 32x32x16 B layout
        int e = i & 7, p = (i >> 3) & 1, kh = (i >> 4) & 1, col = (i >> 5) & 31;
        int nf = (i >> 10) & 3, ks = (i >> 12) & 3, tap = i >> 14;
        int o = nf * 32 + col, ci = ks * 16 + kh * 8 + e;
        float sc = g3[o] * rsqrtf(v3[o] + BN_EPS);
        float wv = c3w[o * 576 + ci * 9 + tap] * sc;
        unsigned short h = rneb(wv);
        w3c2[i] = p ? rneb(wv - b2f(h)) : h;
        return;
    }
    i -= 147456;
    if (i < 32) { float s = g1[i]*rsqrtf(v1[i]+BN_EPS); b1c[i] = (c1b[i]-m1[i])*s + be1[i]; return; }
    i -= 32;
    if (i < 64) { float s = g2[i]*rsqrtf(v2[i]+BN_EPS); b2c[i] = (c2b[i]-m2[i])*s + be2[i]; return; }
    i -= 64;
    if (i < 128) { float s = g3[i]*rsqrtf(v3[i]+BN_EPS); b3c[i] = (c3b[i]-m3[i])*s + be3[i]; return; }
}

// ---------------- fully fused, 1 image/block, 512 thr ----------------
// R1  (20736 u16 = 41472B): conv2-in padded [py18][kc4][px18][e8], hi 0 / lo +10368
//                           reused as conv3-in padded [py10][kc8][px11][e8], hi 0 / lo +7040
// R2x (3074 u32 = 12296B):  x packed (hi<<16|lo) [3][32][32] + zero slot @3072.
//   After P1: float view -> sFeatP[2][128] @0 | sPart[8][64] @256 | sOut[20] @768.
// P2/P3 use 32x32x16 MFMA: half the instructions per FLOP vs 16x16x32
// (R9 showed occupancy is NOT the limiter; per-CU issue is -> cut instructions).
__global__ __launch_bounds__(512, 4) void k_fused(
    const float* __restrict__ x,
    const unsigned short* __restrict__ w1c2,
    const unsigned short* __restrict__ w2c2,
    const unsigned short* __restrict__ w3c2,
    const float* __restrict__ b1c, const float* __restrict__ b2c, const float* __restrict__ b3c,
    const float* __restrict__ w1e, const float* __restrict__ b1e,
    const float* __restrict__ w2e, const float* __restrict__ b2e,
    const float* __restrict__ gw, const float* __restrict__ gb,
    float* __restrict__ out)
{
    __shared__ __align__(16) unsigned short R1[20736];
    __shared__ __align__(16) unsigned int   R2x[3074];
    float* sFeatP = (float*)R2x;         // [2][128] -> materialized sFeat in [0,128)
    float* sPart  = (float*)R2x + 256;   // [8][64]
    float* sOutB  = (float*)R2x + 768;   // [20]

    const int b = blockIdx.x, t = threadIdx.x;
    const int lane = t & 63, w = t >> 6;
    const int l15 = lane & 15, lg = lane >> 4;
    const int4 z4 = {0, 0, 0, 0};

    // ---------------- P0: stage packed x; conv2-in halo zeros ----------------
    {
        const float* xb = x + (size_t)b * 3072;
        for (int i = t; i < 3072; i += 512) {
            float v = xb[i];
            unsigned short h = rneb(v);
            unsigned short lo = rneb(v - b2f(h));
            R2x[i] = ((unsigned)h << 16) | lo;
        }
        if (t == 0) R2x[3072] = 0;
        for (int hh = t; hh < 272; hh += 512) {      // 68 halo (py,px) x 4 kc
            int pr = hh >> 2, kc = hh & 3;
            int py, px;
            if (pr < 36) { py = (pr < 18) ? 0 : 17; px = (pr < 18) ? pr : pr - 18; }
            else { int r = pr - 36; py = 1 + (r >> 1); px = (r & 1) ? 17 : 0; }
            int ei = ((py * 4 + kc) * 18 + px) * 8;
            *(int4*)(R1 + ei) = z4;
            *(int4*)(R1 + 10368 + ei) = z4;
        }
    }
    __syncthreads();

    // ---------------- P1: conv1 (3->32 @32x32) 16x16x32, relu+pool -> conv2-in
    {
        short8 b1h[2], b1l[2];
#pragma unroll
        for (int n = 0; n < 2; n++) {
            const short8* bp = (const short8*)(w1c2 + 16 * ((n * 16 + l15) * 4 + lg));
            b1h[n] = bp[0]; b1l[n] = bp[1];
        }
        int dyE[8], dxE[8], cbE[8];
#pragma unroll
        for (int e = 0; e < 8; e++) {
            int k = lg * 8 + e;
            if (k < 27) { int ci = k / 9, tp = k - ci * 9;
                          dyE[e] = tp / 3 - 1; dxE[e] = tp % 3 - 1; cbE[e] = ci << 10; }
            else { dyE[e] = -1000; dxE[e] = 0; cbE[e] = 0; }
        }
        float bia[2] = { b1c[l15], b1c[16 + l15] };
#pragma unroll 1
        for (int q = 0; q < 2; q++) {
            int m0 = 8 * w + 4 * q;
            f32x4 acc[4][2];
#pragma unroll
            for (int mi = 0; mi < 4; mi++)
#pragma unroll
                for (int n = 0; n < 2; n++) acc[mi][n] = (f32x4)0.f;
#pragma unroll
            for (int mi = 0; mi < 4; mi++) {
                int pos = 16 * (m0 + mi) + l15, py = pos >> 5, px = pos & 31;
                short8 ah, al;
#pragma unroll
                for (int e = 0; e < 8; e++) {
                    int yy = py + dyE[e], xv = px + dxE[e];
                    int idx = cbE[e] + (yy << 5) + xv;
                    bool ok = ((unsigned)yy < 32u) && ((unsigned)xv < 32u);
                    unsigned u = R2x[ok ? idx : 3072];
                    ah[e] = (short)(u >> 16);
                    al[e] = (short)(u & 0xFFFFu);
                }
#pragma unroll
                for (int n = 0; n < 2; n++) {
                    acc[mi][n] = MFMA16(ah, b1h[n], acc[mi][n], 0, 0, 0);
                    acc[mi][n] = MFMA16(ah, b1l[n], acc[mi][n], 0, 0, 0);
                    acc[mi][n] = MFMA16(al, b1h[n], acc[mi][n], 0, 0, 0);
                }
            }
            int PY = 2 * w + q;
#pragma unroll
            for (int n = 0; n < 2; n++) {
                int o = n * 16 + l15;
#pragma unroll
                for (int h = 0; h < 2; h++)
#pragma unroll
                for (int jp = 0; jp < 2; jp++) {
                    float v00 = fmaxf(acc[h][n][2*jp]     + bia[n], 0.f);
                    float v01 = fmaxf(acc[h][n][2*jp + 1] + bia[n], 0.f);
                    float v10 = fmaxf(acc[h+2][n][2*jp]     + bia[n], 0.f);
                    float v11 = fmaxf(acc[h+2][n][2*jp + 1] + bia[n], 0.f);
                    float pm = fmaxf(fmaxf(v00, v01), fmaxf(v10, v11));
                    int PX = h * 8 + lg * 2 + jp;
                    unsigned short ph = rneb(pm), pl = rneb(pm - b2f(ph));
                    int ei = (((PY + 1) * 4 + (o >> 3)) * 18 + (PX + 1)) * 8 + (o & 7);
                    R1[ei] = ph; R1[10368 + ei] = pl;
                }
            }
        }
    }
    __syncthreads();

    // ---------------- P2: conv2 (32->64 @16x16) 32x32x16, in-lane pool --------
    // wave: nt = w&1 (N-tile of 32 oc), wm = w>>1 (M-group: tiles 2wm, 2wm+1).
    // A lane: row r = lane&31 -> (py = 2*mt + (r>>4), px = r&15); k-half kh = lane>>5.
    {
        const int nt = w & 1, wm = w >> 1;
        const int r = lane & 31, kh = lane >> 5;
        f32x16 acc2A = (f32x16)0.f, acc2B = (f32x16)0.f;
        const unsigned short* wb = w2c2 + ((size_t)(nt * 32 + r) * 2 + kh) * 16;
        const int pyb0 = 2 * (2 * wm)     + (r >> 4);
        const int pyb1 = 2 * (2 * wm + 1) + (r >> 4);
        const int pxb = r & 15;
        short8 bhA, blA, bhB, blB;
#define LDBW2(u, BH, BL) { const short8* bp = (const short8*)(wb + (u) * 2048); BH = bp[0]; BL = bp[1]; }
#define CMPW2(u, BH, BL) { const int tap_ = (u) >> 1, ks_ = (u) & 1; \
        const int dy_ = tap_ / 3, dx_ = tap_ - 3 * dy_; \
        const int kc_ = ks_ * 2 + kh; \
        const int co_ = (kc_ * 18 + pxb + dx_) * 8; \
        { int ea_ = (pyb0 + dy_) * 576 + co_; \
          short8 ah_ = *(const short8*)(R1 + ea_); \
          short8 al_ = *(const short8*)(R1 + 10368 + ea_); \
          acc2A = MFMA32(ah_, BH, acc2A, 0, 0, 0); \
          acc2A = MFMA32(ah_, BL, acc2A, 0, 0, 0); \
          acc2A = MFMA32(al_, BH, acc2A, 0, 0, 0); } \
        { int ea_ = (pyb1 + dy_) * 576 + co_; \
          short8 ah_ = *(const short8*)(R1 + ea_); \
          short8 al_ = *(const short8*)(R1 + 10368 + ea_); \
          acc2B = MFMA32(ah_, BH, acc2B, 0, 0, 0); \
          acc2B = MFMA32(ah_, BL, acc2B, 0, 0, 0); \
          acc2B = MFMA32(al_, BH, acc2B, 0, 0, 0); } }
        LDBW2(0, bhA, blA);
#pragma unroll 1
        for (int u = 0; u < 16; u += 2) {
            LDBW2(u + 1, bhB, blB);
            CMPW2(u, bhA, blA);
            LDBW2(u + 2, bhA, blA);
            CMPW2(u + 1, bhB, blB);
        }
        LDBW2(17, bhB, blB);
        CMPW2(16, bhA, blA);
        CMPW2(17, bhB, blB);
        __syncthreads();                 // all conv2-in reads retired
        // conv3-in halo zeros [py10][kc8][px11][e8]
        for (int hh = t; hh < 288; hh += 512) {
            int pr = hh >> 3, kc = hh & 7;
            int py, px;
            if (pr < 20) { py = (pr < 10) ? 0 : 9; px = (pr < 10) ? pr : pr - 10; }
            else { int rr = pr - 20; py = 1 + (rr >> 1); px = (rr & 1) ? 9 : 0; }
            int ei = ((py * 8 + kc) * 11 + px) * 8;
            *(int4*)(R1 + ei) = z4;
            *(int4*)(R1 + 7040 + ei) = z4;
        }
        // epilogue: relu + 2x2 maxpool, fully in-lane (C rows (2g,2g+1,+8) = pool quad)
        {
            int oc = nt * 32 + r;
            float bia = b2c[oc];
#define EPI2(ACC, MT) { \
            _Pragma("unroll") for (int g = 0; g < 4; g++) { \
                float v0 = fmaxf(ACC[2*g]     + bia, 0.f); \
                float v1 = fmaxf(ACC[2*g + 1] + bia, 0.f); \
                float v2 = fmaxf(ACC[2*g + 8] + bia, 0.f); \
                float v3 = fmaxf(ACC[2*g + 9] + bia, 0.f); \
                float pm = fmaxf(fmaxf(v0, v1), fmaxf(v2, v3)); \
                int PX = (g & 1) + (g >> 1) * 4 + kh * 2; \
                int ei = ((((MT) + 1) * 8 + (oc >> 3)) * 11 + (PX + 1)) * 8 + (oc & 7); \
                unsigned short ph = rneb(pm); \
                R1[ei] = ph; R1[7040 + ei] = rneb(pm - b2f(ph)); } }
            EPI2(acc2A, 2 * wm);
            EPI2(acc2B, 2 * wm + 1);
        }
    }
    __syncthreads();

    // ---------------- P3: conv3 (64->128 @8x8) 32x32x16, in-lane pool+avg -----
    // wave: mt = w>>2 (M-tile: image rows 4mt..4mt+3), nf = w&3 (N-tile of 32 oc).
    {
        const int mt = w >> 2, nf = w & 3;
        const int r = lane & 31, kh = lane >> 5;
        f32x16 acc3 = (f32x16)0.f;
        const unsigned short* wb3 = w3c2 + ((size_t)(nf * 32 + r) * 2 + kh) * 16;
        const int pyb = mt * 4 + (r >> 3), pxb = r & 7;
        short8 bhA, blA, bhB, blB;
#define LDBW3(u, BH, BL) { const short8* bp = (const short8*)(wb3 + (u) * 4096); BH = bp[0]; BL = bp[1]; }
#define CMPW3(u, BH, BL) { const int tap_ = (u) >> 2, ks_ = (u) & 3; \
        const int dy_ = tap_ / 3, dx_ = tap_ - 3 * dy_; \
        const int kc_ = ks_ * 2 + kh; \
        int ea_ = (((pyb + dy_) * 8 + kc_) * 11 + (pxb + dx_)) * 8; \
        short8 ah_ = *(const short8*)(R1 + ea_); \
        short8 al_ = *(const short8*)(R1 + 7040 + ea_); \
        acc3 = MFMA32(ah_, BH, acc3, 0, 0, 0); \
        acc3 = MFMA32(ah_, BL, acc3, 0, 0, 0); \
        acc3 = MFMA32(al_, BH, acc3, 0, 0, 0); }
        LDBW3(0, bhA, blA);
#pragma unroll 1
        for (int u = 0; u < 34; u += 2) {
            LDBW3(u + 1, bhB, blB);
            CMPW3(u, bhA, blA);
            LDBW3(u + 2, bhA, blA);
            CMPW3(u + 1, bhB, blB);
        }
        LDBW3(35, bhB, blB);
        CMPW3(34, bhA, blA);
        CMPW3(35, bhB, blB);
        // epilogue: relu + 2x2 maxpool + partial avg, in-lane; xor32 merges kh halves
        {
            int oc = nf * 32 + r;
            float bia = b3c[oc];
            float fs = 0.f;
#pragma unroll
            for (int pl = 0; pl < 2; pl++)
#pragma unroll
            for (int g = 0; g < 2; g++) {
                float v0 = fmaxf(acc3[pl*8 + 2*g]     + bia, 0.f);
                float v1 = fmaxf(acc3[pl*8 + 2*g + 1] + bia, 0.f);
                float v2 = fmaxf(acc3[pl*8 + 2*g + 4] + bia, 0.f);
                float v3 = fmaxf(acc3[pl*8 + 2*g + 5] + bia, 0.f);
                fs += fmaxf(fmaxf(v0, v1), fmaxf(v2, v3));
            }
            fs += __shfl_xor(fs, 32, 64);
            if (lane < 32) sFeatP[mt * 128 + oc] = fs;
        }
    }
    __syncthreads();
    if (t < 128) sFeatP[t] = (sFeatP[t] + sFeatP[128 + t]) * (1.0f / 16.0f);
    __syncthreads();

    // ---------------- P4: gate top-2 (all waves) + split expert MLPs ----------
    int i1 = 0, i2 = 0;
    float wk1 = 0.f, wk2 = 0.f;
    {
        float f0 = sFeatP[lane], f1 = sFeatP[64 + lane];
        float lgt[8];
#pragma unroll
        for (int e = 0; e < 8; e++) {
            float p = f0 * gw[lane * 8 + e] + f1 * gw[(64 + lane) * 8 + e];
#pragma unroll
            for (int s = 1; s < 64; s <<= 1) p += __shfl_xor(p, s, 64);
            lgt[e] = p + gb[e];
        }
        float v1m = -1e30f, v2m = -1e30f;
#pragma unroll
        for (int e = 0; e < 8; e++) {
            float le = lgt[e];
            if (le > v1m) { v2m = v1m; i2 = i1; v1m = le; i1 = e; }
            else if (le > v2m) { v2m = le; i2 = e; }
        }
        float ex = expf(v2m - v1m);
        wk1 = 1.f / (1.f + ex); wk2 = ex / (1.f + ex);
        int e = (w < 4) ? i1 : i2;
        int k0 = (w & 3) * 32;
        const float* W1 = w1e + (size_t)e * 8192 + (size_t)k0 * 64;
        float hj = 0.f;
#pragma unroll 8
        for (int kk = 0; kk < 32; kk++) hj += sFeatP[k0 + kk] * W1[kk * 64 + lane];
        sPart[w * 64 + lane] = hj;
    }
    __syncthreads();
    if (w < 2) {
        int e = (w == 0) ? i1 : i2;
        float wk = (w == 0) ? wk1 : wk2;
        float hj = b1e[e * 64 + lane]
                 + sPart[(w * 4 + 0) * 64 + lane] + sPart[(w * 4 + 1) * 64 + lane]
                 + sPart[(w * 4 + 2) * 64 + lane] + sPart[(w * 4 + 3) * 64 + lane];
        hj = fmaxf(hj, 0.f);
        const float* W2 = w2e + (size_t)e * 640 + lane * 10;
#pragma unroll
        for (int o = 0; o < 10; o++) {
            float po = hj * W2[o];
#pragma unroll
            for (int s = 1; s < 64; s <<= 1) po += __shfl_xor(po, s, 64);
            if (lane == 0) sOutB[w * 10 + o] = wk * (po + b2e[e * 10 + o]);
        }
    }
    __syncthreads();
    if (t < 10) out[(size_t)b * 10 + t] = sOutB[t] + sOutB[10 + t];
}

extern "C" void kernel_launch(void* const* d_in, const int* in_sizes, int n_in,
                              void* d_out, int out_size, void* d_ws, size_t ws_size,
                              hipStream_t stream)
{
    const float* x   = (const float*)d_in[0];
    const float* c1w = (const float*)d_in[1];
    const float* c1b = (const float*)d_in[2];
    const float* g1  = (const float*)d_in[3];
    const float* be1 = (const float*)d_in[4];
    const float* m1  = (const float*)d_in[5];
    const float* v1  = (const float*)d_in[6];
    const float* c2w = (const float*)d_in[7];
    const float* c2b = (const float*)d_in[8];
    const float* g2  = (const float*)d_in[9];
    const float* be2 = (const float*)d_in[10];
    const float* m2  = (const float*)d_in[11];
    const float* v2  = (const float*)d_in[12];
    const float* c3w = (const float*)d_in[13];
    const float* c3b = (const float*)d_in[14];
    const float* g3  = (const float*)d_in[15];
    const float* be3 = (const float*)d_in[16];
    const float* m3  = (const float*)d_in[17];
    const float* v3  = (const float*)d_in[18];
    const float* w1e = (const float*)d_in[19];
    const float* b1e = (const float*)d_in[20];
    const float* w2e = (const float*)d_in[21];
    const float* b2e = (const float*)d_in[22];
    const float* gw  = (const float*)d_in[23];
    const float* gb  = (const float*)d_in[24];

    float* ws = (float*)d_ws;
    unsigned short* w1c2 = (unsigned short*)(ws + W1C2_OFF);
    unsigned short* w2c2 = (unsigned short*)(ws + W2C2_OFF);
    unsigned short* w3c2 = (unsigned short*)(ws + W3C2_OFF);
    float* b1c = ws + B1_OFF;
    float* b2c = ws + B2_OFF;
    float* b3c = ws + B3_OFF;

    k_prep<<<729, 256, 0, stream>>>(c1w, c2w, c3w,
                                    c1b, g1, be1, m1, v1,
                                    c2b, g2, be2, m2, v2,
                                    c3b, g3, be3, m3, v3,
                                    w1c2, w2c2, w3c2, b1c, b2c, b3c);
    k_fused<<<4096, 512, 0, stream>>>(x, w1c2, w2c2, w3c2, b1c, b2c, b3c,
                                      w1e, b1e, w2e, b2e, gw, gb, (float*)d_out);
}